// Round 7
// baseline (393.072 us; speedup 1.0000x reference)
//
#include <hip/hip_runtime.h>
#include <math.h>

#define DIM 1024
#define NHEAD 16
#define HD 64
#define HIDDEN 4096
#define SEQ 1024
#define BATCH 4
#define ROWS (BATCH*SEQ)   // 4096 tokens

typedef __attribute__((ext_vector_type(8))) short bf16x8;
typedef __attribute__((ext_vector_type(4))) float f32x4;
typedef __attribute__((ext_vector_type(4))) unsigned short us4;

__device__ __forceinline__ unsigned short f2bf(float f) {
  unsigned u = __builtin_bit_cast(unsigned, f);
  u += 0x7fffu + ((u >> 16) & 1u);           // round-to-nearest-even
  return (unsigned short)(u >> 16);
}

__device__ __forceinline__ void glds16(const void* g, void* l) {
  __builtin_amdgcn_global_load_lds((const __attribute__((address_space(1))) void*)g,
                                   (__attribute__((address_space(3))) void*)l,
                                   16, 0, 0);
}

// ---------------- fp32 -> bf16 weight conversion (all 4 weights, one launch) ----------------
__global__ void cvt_all(const float* __restrict__ a, const float* __restrict__ b,
                        const float* __restrict__ c, const float* __restrict__ d,
                        unsigned short* __restrict__ oa, unsigned short* __restrict__ ob,
                        unsigned short* __restrict__ oc, unsigned short* __restrict__ od) {
  const int na = 3 * DIM * DIM / 4, nb = DIM * DIM / 4, nc = HIDDEN * DIM / 4, nd = DIM * HIDDEN / 4;
  const int total = na + nb + nc + nd;
  for (int i = blockIdx.x * blockDim.x + threadIdx.x; i < total; i += gridDim.x * blockDim.x) {
    const float* in; unsigned short* out; int j = i;
    if (j < na)             { in = a; out = oa; }
    else if ((j -= na) < nb){ in = b; out = ob; }
    else if ((j -= nb) < nc){ in = c; out = oc; }
    else                    { j -= nc; in = d; out = od; }
    float4 v = reinterpret_cast<const float4*>(in)[j];
    us4 o = { f2bf(v.x), f2bf(v.y), f2bf(v.z), f2bf(v.w) };
    reinterpret_cast<us4*>(out)[j] = o;
  }
}

// ---------------- LayerNorm: fp32 row -> bf16 normalized ----------------
__global__ void ln_kernel(const float* __restrict__ x, const float* __restrict__ w,
                          const float* __restrict__ b, unsigned short* __restrict__ out) {
  int row = blockIdx.x;
  const float* xr = x + (size_t)row * DIM;
  int t = threadIdx.x;
  float4 v = *reinterpret_cast<const float4*>(xr + t * 4);
  float s  = v.x + v.y + v.z + v.w;
  float s2 = v.x*v.x + v.y*v.y + v.z*v.z + v.w*v.w;
#pragma unroll
  for (int m = 1; m < 64; m <<= 1) { s += __shfl_xor(s, m); s2 += __shfl_xor(s2, m); }
  __shared__ float red[8];
  int wv = t >> 6, ln = t & 63;
  if (ln == 0) { red[wv] = s; red[4 + wv] = s2; }
  __syncthreads();
  s  = red[0] + red[1] + red[2] + red[3];
  s2 = red[4] + red[5] + red[6] + red[7];
  float mu  = s * (1.0f / DIM);
  float var = s2 * (1.0f / DIM) - mu * mu;
  float rs  = rsqrtf(var + 1e-5f);
  float4 wv4 = *reinterpret_cast<const float4*>(w + t * 4);
  float4 bv4 = *reinterpret_cast<const float4*>(b + t * 4);
  us4 o = { f2bf((v.x - mu) * rs * wv4.x + bv4.x),
            f2bf((v.y - mu) * rs * wv4.y + bv4.y),
            f2bf((v.z - mu) * rs * wv4.z + bv4.z),
            f2bf((v.w - mu) * rs * wv4.w + bv4.w) };
  *reinterpret_cast<us4*>(out + (size_t)row * DIM + t * 4) = o;
}

// ---------------- 128xBN bf16 NT GEMM, 2-phase double-buffered (R5 proven), fused epilogues ----------------
// stage(next) issued BEFORE compute(cur); the single __syncthreads per K-step drains the
// prefetch issued a full compute-phase earlier.
// MODE 0: QKV  -> writes q (bias+scale), k, vT   (bf16)
// MODE 1: proj -> outf = acc + bias + resid      (fp32, = x_res)
// MODE 2: mlp1 -> outh = gelu(acc + bias)        (bf16)
// MODE 3: mlp2 -> outf = acc + bias + resid      (fp32, = final out)
template<int MODE, int BN>
__global__ __launch_bounds__(256)
void gemm128(const unsigned short* __restrict__ A, const unsigned short* __restrict__ Bw,
             int K, int N,
             const float* __restrict__ bias, const float* __restrict__ resid,
             float* __restrict__ outf, unsigned short* __restrict__ outh,
             unsigned short* __restrict__ qo, unsigned short* __restrict__ ko,
             unsigned short* __restrict__ vto,
             const float* __restrict__ qbias, const float* __restrict__ vbias)
{
  constexpr int NJ = BN / 32;                 // B-frags per wave
  __shared__ unsigned short smA[2][128 * 32];
  __shared__ unsigned short smB[2][BN * 32];
  const int tid = threadIdx.x;
  const int wv = tid >> 6, ln = tid & 63;
  const int tile_m = blockIdx.x * 128, tile_n = blockIdx.y * BN;
  const int wm = (wv >> 1) * 64, wn = (wv & 1) * (BN / 2);

  const unsigned short* gA = A  + (size_t)(tile_m + wv * 32 + (ln >> 2)) * K + (ln & 3) * 8;
  const unsigned short* gB = Bw + (size_t)(tile_n + wv * (BN / 4) + (ln >> 2)) * K + (ln & 3) * 8;

  f32x4 acc[4][NJ] = {};
  const int lr = ln & 15, lc8 = (ln >> 4) * 8;

  auto stage = [&](int buf, int k0) {
    glds16(gA + k0,                  &smA[buf][wv * 1024]);
    glds16(gA + k0 + 16 * (size_t)K, &smA[buf][wv * 1024 + 512]);
    glds16(gB + k0,                  &smB[buf][wv * (BN / 4) * 32]);
    if (BN == 128) glds16(gB + k0 + 16 * (size_t)K, &smB[buf][wv * 1024 + 512]);
  };

  stage(0, 0);
  __syncthreads();                 // prologue drain (one-time full vmcnt wait)
  int cur = 0;
  for (int k0 = 0; k0 < K; k0 += 32) {
    if (k0 + 32 < K) stage(cur ^ 1, k0 + 32);   // issue next tile FIRST
    bf16x8 af[4], bfr[NJ];
#pragma unroll
    for (int i = 0; i < 4; i++)
      af[i] = *reinterpret_cast<const bf16x8*>(&smA[cur][(wm + i * 16 + lr) * 32 + lc8]);
#pragma unroll
    for (int j = 0; j < NJ; j++)
      bfr[j] = *reinterpret_cast<const bf16x8*>(&smB[cur][(wn + j * 16 + lr) * 32 + lc8]);
#pragma unroll
    for (int i = 0; i < 4; i++)
#pragma unroll
      for (int j = 0; j < NJ; j++)
        acc[i][j] = __builtin_amdgcn_mfma_f32_16x16x32_bf16(af[i], bfr[j], acc[i][j], 0, 0, 0);
    __syncthreads();               // drains the prefetch issued above + barrier
    cur ^= 1;
  }

  const int lcol = ln & 15, lrow4 = (ln >> 4) * 4;
#pragma unroll
  for (int i = 0; i < 4; i++) {
#pragma unroll
    for (int j = 0; j < NJ; j++) {
      int gm0 = tile_m + wm + i * 16 + lrow4;
      int gn  = tile_n + wn + j * 16 + lcol;
#pragma unroll
      for (int r = 0; r < 4; r++) {
        int gm = gm0 + r;
        float val = acc[i][j][r];
        if (MODE == 0) {
          int b = gm >> 10, n = gm & 1023;
          if (gn < DIM) {
            float q = (val + qbias[gn]) * 0.125f;   // HD^-0.5 = 0.125
            qo[(size_t)((b * NHEAD + (gn >> 6)) * SEQ + n) * HD + (gn & 63)] = f2bf(q);
          } else if (gn < 2 * DIM) {
            int g2 = gn - DIM;
            ko[(size_t)((b * NHEAD + (g2 >> 6)) * SEQ + n) * HD + (g2 & 63)] = f2bf(val);
          } else {
            int g3 = gn - 2 * DIM;
            vto[(size_t)((b * NHEAD + (g3 >> 6)) * HD + (g3 & 63)) * SEQ + n] = f2bf(val + vbias[g3]);
          }
        } else if (MODE == 1) {
          outf[(size_t)gm * N + gn] = val + bias[gn] + resid[(size_t)gm * N + gn];
        } else if (MODE == 2) {
          float t = val + bias[gn];
          float g = 0.5f * t * (1.0f + erff(t * 0.70710678118f));
          outh[(size_t)gm * N + gn] = f2bf(g);
        } else {
          outf[(size_t)gm * N + gn] = val + bias[gn] + resid[(size_t)gm * N + gn];
        }
      }
    }
  }
}

// ---------------- flash attention: barrier-free, direct-L2 K/V reads ----------------
// K/V per head = 256KB -> L2-resident (common-mistake #7: do NOT stage what L2 fits).
// 256 threads = 4 independent waves, 16 q-rows each; NO __syncthreads in the k-loop.
// S^T layout: lane holds q=lane&15, k = kt + j*16 + (lane>>4)*4 + r.
// K+bias+mask loads issued together at step top; V loads in flight under softmax.
// T13 defer-max: skip O-rescale while __all(pm - m <= 8).
__global__ __launch_bounds__(256)
void attn_kernel(const unsigned short* __restrict__ qg, const unsigned short* __restrict__ kg,
                 const unsigned short* __restrict__ vtg, const float* __restrict__ rpb,
                 const int* __restrict__ amask, unsigned short* __restrict__ outh)
{
  constexpr int PSTR = 72;
  __shared__ unsigned short pls[4][16 * PSTR]; // per-wave P tile (wave-private)
  const int tid = threadIdx.x;
  const int wv = tid >> 6, ln = tid & 63;
  const int bh = blockIdx.y, b = bh >> 4, h = bh & 15;
  const int q0 = blockIdx.x * 64 + wv * 16;
  const unsigned short* qb = qg  + (size_t)bh * SEQ * HD;
  const unsigned short* kb = kg  + (size_t)bh * SEQ * HD;
  const unsigned short* vb = vtg + (size_t)bh * HD * SEQ;
  const int* mp = amask + b * SEQ;
  unsigned short* myp = pls[wv];

  const int lcol = ln & 15, g = ln >> 4, lc8 = g * 8, lrow4 = g * 4;
  const float* bprow = rpb + (size_t)h * SEQ * SEQ + (size_t)(q0 + lcol) * SEQ;

  bf16x8 aq0 = *reinterpret_cast<const bf16x8*>(qb + (size_t)(q0 + lcol) * HD + lc8);
  bf16x8 aq1 = *reinterpret_cast<const bf16x8*>(qb + (size_t)(q0 + lcol) * HD + 32 + lc8);

  f32x4 o[4] = {};
  float m = -1e30f, l = 0.f;

  for (int kt = 0; kt < SEQ; kt += 64) {
    // K fragments + bias + mask: issue together (independent; single latency exposure)
    bf16x8 kf0[4], kf1[4];
    float4 bv4[4]; int4 mv[4];
#pragma unroll
    for (int j = 0; j < 4; j++) {
      const unsigned short* kp = kb + (size_t)(kt + j * 16 + lcol) * HD + lc8;
      kf0[j] = *reinterpret_cast<const bf16x8*>(kp);
      kf1[j] = *reinterpret_cast<const bf16x8*>(kp + 32);
      bv4[j] = *reinterpret_cast<const float4*>(bprow + kt + j * 16 + lrow4);
      mv[j]  = *reinterpret_cast<const int4*>(mp + kt + j * 16 + lrow4);
    }
    f32x4 s[4];
    __builtin_amdgcn_s_setprio(1);
#pragma unroll
    for (int j = 0; j < 4; j++) {
      f32x4 z = {0.f, 0.f, 0.f, 0.f};
      z = __builtin_amdgcn_mfma_f32_16x16x32_bf16(kf0[j], aq0, z, 0, 0, 0);  // A=K, B=Q -> S^T
      z = __builtin_amdgcn_mfma_f32_16x16x32_bf16(kf1[j], aq1, z, 0, 0, 0);
      s[j] = z;
    }
    __builtin_amdgcn_s_setprio(0);
    // V fragments: in flight during softmax
    bf16x8 vf[2][4];
#pragma unroll
    for (int c = 0; c < 2; c++)
#pragma unroll
      for (int d = 0; d < 4; d++)
        vf[c][d] = *reinterpret_cast<const bf16x8*>(vb + (size_t)(d * 16 + lcol) * SEQ + kt + c * 32 + lc8);
    // bias + key-padding mask (finite sentinel avoids NaN)
#pragma unroll
    for (int j = 0; j < 4; j++) {
      s[j][0] = mv[j].x ? s[j][0] + bv4[j].x : -1e30f;
      s[j][1] = mv[j].y ? s[j][1] + bv4[j].y : -1e30f;
      s[j][2] = mv[j].z ? s[j][2] + bv4[j].z : -1e30f;
      s[j][3] = mv[j].w ? s[j][3] + bv4[j].w : -1e30f;
    }
    float pm = fmaxf(fmaxf(fmaxf(s[0][0], s[0][1]), fmaxf(s[0][2], s[0][3])),
                     fmaxf(fmaxf(s[1][0], s[1][1]), fmaxf(s[1][2], s[1][3])));
    pm = fmaxf(pm, fmaxf(fmaxf(fmaxf(s[2][0], s[2][1]), fmaxf(s[2][2], s[2][3])),
                         fmaxf(fmaxf(s[3][0], s[3][1]), fmaxf(s[3][2], s[3][3]))));
    pm = fmaxf(pm, __shfl_xor(pm, 16));
    pm = fmaxf(pm, __shfl_xor(pm, 32));
    // T13 defer-max: rescale only on real max growth (P bounded by e^8 otherwise)
    if (!__all(pm - m <= 8.0f)) {
      float mn = fmaxf(m, pm);
      float fr = __expf(m - mn);
      m = mn;
      l *= fr;
      float frq[4];
#pragma unroll
      for (int r = 0; r < 4; r++) frq[r] = __shfl(fr, lrow4 + r);
#pragma unroll
      for (int d = 0; d < 4; d++)
#pragma unroll
        for (int r = 0; r < 4; r++) o[d][r] *= frq[r];
    }
    float rs = 0.f;
#pragma unroll
    for (int j = 0; j < 4; j++)
#pragma unroll
      for (int r = 0; r < 4; r++) {
        float p = __expf(s[j][r] - m);
        s[j][r] = p;
        rs += p;
      }
    rs += __shfl_xor(rs, 16);
    rs += __shfl_xor(rs, 32);
    l += rs;
    // P -> LDS [q][k] (packed 8B stores), read back as A-fragment (wave-private, in-order DS)
#pragma unroll
    for (int j = 0; j < 4; j++) {
      us4 po = { f2bf(s[j][0]), f2bf(s[j][1]), f2bf(s[j][2]), f2bf(s[j][3]) };
      *reinterpret_cast<us4*>(myp + lcol * PSTR + j * 16 + lrow4) = po;
    }
    asm volatile("s_waitcnt lgkmcnt(0)" ::: "memory");
    __builtin_amdgcn_sched_barrier(0);
    __builtin_amdgcn_s_setprio(1);
#pragma unroll
    for (int c = 0; c < 2; c++) {
      bf16x8 ap = *reinterpret_cast<const bf16x8*>(myp + lcol * PSTR + c * 32 + lc8);
#pragma unroll
      for (int d = 0; d < 4; d++)
        o[d] = __builtin_amdgcn_mfma_f32_16x16x32_bf16(ap, vf[c][d], o[d], 0, 0, 0);
    }
    __builtin_amdgcn_s_setprio(0);
  }
  float linv = 1.0f / l;
  float lq[4];
#pragma unroll
  for (int r = 0; r < 4; r++) lq[r] = __shfl(linv, lrow4 + r);
#pragma unroll
  for (int d = 0; d < 4; d++)
#pragma unroll
    for (int r = 0; r < 4; r++)
      outh[(size_t)(b * SEQ + q0 + lrow4 + r) * DIM + h * HD + d * 16 + lcol] = f2bf(o[d][r] * lq[r]);
}

// ---------------- host ----------------
extern "C" void kernel_launch(void* const* d_in, const int* in_sizes, int n_in,
                              void* d_out, int out_size, void* d_ws, size_t ws_size,
                              hipStream_t stream)
{
  const float* x      = (const float*)d_in[0];
  const float* rpb    = (const float*)d_in[1];
  const int*   amask  = (const int*)d_in[2];
  const float* n1w    = (const float*)d_in[3];
  const float* n1b    = (const float*)d_in[4];
  const float* qkv_w  = (const float*)d_in[5];
  const float* q_bias = (const float*)d_in[6];
  const float* v_bias = (const float*)d_in[7];
  const float* proj_w = (const float*)d_in[8];
  const float* proj_b = (const float*)d_in[9];
  const float* n2w    = (const float*)d_in[10];
  const float* n2b    = (const float*)d_in[11];
  const float* w1     = (const float*)d_in[12];
  const float* b1     = (const float*)d_in[13];
  const float* w2     = (const float*)d_in[14];
  const float* b2     = (const float*)d_in[15];
  float* out = (float*)d_out;

  char* ws = (char*)d_ws;
  size_t off = 0;
  auto alloc = [&](size_t bytes) { char* p = ws + off; off += (bytes + 255) & ~(size_t)255; return p; };
  unsigned short* xn1    = (unsigned short*)alloc((size_t)ROWS * DIM * 2);
  unsigned short* xn2    = (unsigned short*)alloc((size_t)ROWS * DIM * 2);
  unsigned short* wqkv_h = (unsigned short*)alloc((size_t)3 * DIM * DIM * 2);
  unsigned short* wproj_h= (unsigned short*)alloc((size_t)DIM * DIM * 2);
  unsigned short* w1_h   = (unsigned short*)alloc((size_t)HIDDEN * DIM * 2);
  unsigned short* w2_h   = (unsigned short*)alloc((size_t)DIM * HIDDEN * 2);
  unsigned short* qh     = (unsigned short*)alloc((size_t)ROWS * DIM * 2);
  unsigned short* kh     = (unsigned short*)alloc((size_t)ROWS * DIM * 2);
  unsigned short* vth    = (unsigned short*)alloc((size_t)ROWS * DIM * 2);
  unsigned short* attn_h = (unsigned short*)alloc((size_t)ROWS * DIM * 2);
  float*          xres   = (float*)alloc((size_t)ROWS * DIM * 4);
  unsigned short* hmid   = (unsigned short*)alloc((size_t)ROWS * HIDDEN * 2);

  // all weight conversions in one launch
  cvt_all<<<2048, 256, 0, stream>>>(qkv_w, proj_w, w1, w2, wqkv_h, wproj_h, w1_h, w2_h);

  // LN1
  ln_kernel<<<ROWS, 256, 0, stream>>>(x, n1w, n1b, xn1);
  // QKV GEMM (M=4096, N=3072, K=1024) -- 768 blocks
  gemm128<0, 128><<<dim3(ROWS / 128, 3 * DIM / 128), 256, 0, stream>>>(
      xn1, wqkv_h, DIM, 3 * DIM, nullptr, nullptr, nullptr, nullptr, qh, kh, vth, q_bias, v_bias);
  // attention -- 1024 blocks x 256 threads, barrier-free
  attn_kernel<<<dim3(SEQ / 64, BATCH * NHEAD), 256, 0, stream>>>(qh, kh, vth, rpb, amask, attn_h);
  // proj GEMM + residual -> x_res (fp32) -- BN=64 -> 512 blocks
  gemm128<1, 64><<<dim3(ROWS / 128, DIM / 64), 256, 0, stream>>>(
      attn_h, wproj_h, DIM, DIM, proj_b, x, xres, nullptr, nullptr, nullptr, nullptr, nullptr, nullptr);
  // LN2
  ln_kernel<<<ROWS, 256, 0, stream>>>(xres, n2w, n2b, xn2);
  // MLP1 + GELU -- 1024 blocks
  gemm128<2, 128><<<dim3(ROWS / 128, HIDDEN / 128), 256, 0, stream>>>(
      xn2, w1_h, DIM, HIDDEN, b1, nullptr, nullptr, hmid, nullptr, nullptr, nullptr, nullptr, nullptr);
  // MLP2 + residual -> out -- BN=64 -> 512 blocks
  gemm128<3, 64><<<dim3(ROWS / 128, DIM / 64), 256, 0, stream>>>(
      hmid, w2_h, HIDDEN, DIM, b2, xres, out, nullptr, nullptr, nullptr, nullptr, nullptr, nullptr);
}

// Round 8
// 371.197 us; speedup vs baseline: 1.0589x; 1.0589x over previous
//
#include <hip/hip_runtime.h>
#include <math.h>

#define DIM 1024
#define NHEAD 16
#define HD 64
#define HIDDEN 4096
#define SEQ 1024
#define BATCH 4
#define ROWS (BATCH*SEQ)   // 4096 tokens

typedef __attribute__((ext_vector_type(8))) short bf16x8;
typedef __attribute__((ext_vector_type(4))) float f32x4;
typedef __attribute__((ext_vector_type(4))) unsigned short us4;

__device__ __forceinline__ unsigned short f2bf(float f) {
  unsigned u = __builtin_bit_cast(unsigned, f);
  u += 0x7fffu + ((u >> 16) & 1u);           // round-to-nearest-even
  return (unsigned short)(u >> 16);
}

__device__ __forceinline__ void glds16(const void* g, void* l) {
  __builtin_amdgcn_global_load_lds((const __attribute__((address_space(1))) void*)g,
                                   (__attribute__((address_space(3))) void*)l,
                                   16, 0, 0);
}

// ---------------- fp32 -> bf16 weight conversion (all 4 weights, one launch) ----------------
__global__ void cvt_all(const float* __restrict__ a, const float* __restrict__ b,
                        const float* __restrict__ c, const float* __restrict__ d,
                        unsigned short* __restrict__ oa, unsigned short* __restrict__ ob,
                        unsigned short* __restrict__ oc, unsigned short* __restrict__ od) {
  const int na = 3 * DIM * DIM / 4, nb = DIM * DIM / 4, nc = HIDDEN * DIM / 4, nd = DIM * HIDDEN / 4;
  const int total = na + nb + nc + nd;
  for (int i = blockIdx.x * blockDim.x + threadIdx.x; i < total; i += gridDim.x * blockDim.x) {
    const float* in; unsigned short* out; int j = i;
    if (j < na)             { in = a; out = oa; }
    else if ((j -= na) < nb){ in = b; out = ob; }
    else if ((j -= nb) < nc){ in = c; out = oc; }
    else                    { j -= nc; in = d; out = od; }
    float4 v = reinterpret_cast<const float4*>(in)[j];
    us4 o = { f2bf(v.x), f2bf(v.y), f2bf(v.z), f2bf(v.w) };
    reinterpret_cast<us4*>(out)[j] = o;
  }
}

// ---------------- LayerNorm: fp32 row -> bf16 normalized ----------------
__global__ void ln_kernel(const float* __restrict__ x, const float* __restrict__ w,
                          const float* __restrict__ b, unsigned short* __restrict__ out) {
  int row = blockIdx.x;
  const float* xr = x + (size_t)row * DIM;
  int t = threadIdx.x;
  float4 v = *reinterpret_cast<const float4*>(xr + t * 4);
  float s  = v.x + v.y + v.z + v.w;
  float s2 = v.x*v.x + v.y*v.y + v.z*v.z + v.w*v.w;
#pragma unroll
  for (int m = 1; m < 64; m <<= 1) { s += __shfl_xor(s, m); s2 += __shfl_xor(s2, m); }
  __shared__ float red[8];
  int wv = t >> 6, ln = t & 63;
  if (ln == 0) { red[wv] = s; red[4 + wv] = s2; }
  __syncthreads();
  s  = red[0] + red[1] + red[2] + red[3];
  s2 = red[4] + red[5] + red[6] + red[7];
  float mu  = s * (1.0f / DIM);
  float var = s2 * (1.0f / DIM) - mu * mu;
  float rs  = rsqrtf(var + 1e-5f);
  float4 wv4 = *reinterpret_cast<const float4*>(w + t * 4);
  float4 bv4 = *reinterpret_cast<const float4*>(b + t * 4);
  us4 o = { f2bf((v.x - mu) * rs * wv4.x + bv4.x),
            f2bf((v.y - mu) * rs * wv4.y + bv4.y),
            f2bf((v.z - mu) * rs * wv4.z + bv4.z),
            f2bf((v.w - mu) * rs * wv4.w + bv4.w) };
  *reinterpret_cast<us4*>(out + (size_t)row * DIM + t * 4) = o;
}

// ---------------- 128xBN bf16 NT GEMM, 2-phase double-buffered (R5 proven), fused epilogues ----------------
// MODE 0: QKV  -> writes q (bias+scale), k, vT   (bf16)
// MODE 1: proj -> outf = acc + bias + resid      (fp32, = x_res)
// MODE 2: mlp1 -> outh = gelu(acc + bias)        (bf16)
// MODE 3: mlp2 -> outf = acc + bias + resid      (fp32, = final out)
template<int MODE, int BN>
__global__ __launch_bounds__(256)
void gemm128(const unsigned short* __restrict__ A, const unsigned short* __restrict__ Bw,
             int K, int N,
             const float* __restrict__ bias, const float* __restrict__ resid,
             float* __restrict__ outf, unsigned short* __restrict__ outh,
             unsigned short* __restrict__ qo, unsigned short* __restrict__ ko,
             unsigned short* __restrict__ vto,
             const float* __restrict__ qbias, const float* __restrict__ vbias)
{
  constexpr int NJ = BN / 32;                 // B-frags per wave
  __shared__ unsigned short smA[2][128 * 32];
  __shared__ unsigned short smB[2][BN * 32];
  const int tid = threadIdx.x;
  const int wv = tid >> 6, ln = tid & 63;
  const int tile_m = blockIdx.x * 128, tile_n = blockIdx.y * BN;
  const int wm = (wv >> 1) * 64, wn = (wv & 1) * (BN / 2);

  const unsigned short* gA = A  + (size_t)(tile_m + wv * 32 + (ln >> 2)) * K + (ln & 3) * 8;
  const unsigned short* gB = Bw + (size_t)(tile_n + wv * (BN / 4) + (ln >> 2)) * K + (ln & 3) * 8;

  f32x4 acc[4][NJ] = {};
  const int lr = ln & 15, lc8 = (ln >> 4) * 8;

  auto stage = [&](int buf, int k0) {
    glds16(gA + k0,                  &smA[buf][wv * 1024]);
    glds16(gA + k0 + 16 * (size_t)K, &smA[buf][wv * 1024 + 512]);
    glds16(gB + k0,                  &smB[buf][wv * (BN / 4) * 32]);
    if (BN == 128) glds16(gB + k0 + 16 * (size_t)K, &smB[buf][wv * 1024 + 512]);
  };

  stage(0, 0);
  __syncthreads();                 // prologue drain (one-time full vmcnt wait)
  int cur = 0;
  for (int k0 = 0; k0 < K; k0 += 32) {
    if (k0 + 32 < K) stage(cur ^ 1, k0 + 32);   // issue next tile FIRST
    bf16x8 af[4], bfr[NJ];
#pragma unroll
    for (int i = 0; i < 4; i++)
      af[i] = *reinterpret_cast<const bf16x8*>(&smA[cur][(wm + i * 16 + lr) * 32 + lc8]);
#pragma unroll
    for (int j = 0; j < NJ; j++)
      bfr[j] = *reinterpret_cast<const bf16x8*>(&smB[cur][(wn + j * 16 + lr) * 32 + lc8]);
#pragma unroll
    for (int i = 0; i < 4; i++)
#pragma unroll
      for (int j = 0; j < NJ; j++)
        acc[i][j] = __builtin_amdgcn_mfma_f32_16x16x32_bf16(af[i], bfr[j], acc[i][j], 0, 0, 0);
    __syncthreads();               // drains the prefetch issued above + barrier
    cur ^= 1;
  }

  const int lcol = ln & 15, lrow4 = (ln >> 4) * 4;
#pragma unroll
  for (int i = 0; i < 4; i++) {
#pragma unroll
    for (int j = 0; j < NJ; j++) {
      int gm0 = tile_m + wm + i * 16 + lrow4;
      int gn  = tile_n + wn + j * 16 + lcol;
#pragma unroll
      for (int r = 0; r < 4; r++) {
        int gm = gm0 + r;
        float val = acc[i][j][r];
        if (MODE == 0) {
          int b = gm >> 10, n = gm & 1023;
          if (gn < DIM) {
            float q = (val + qbias[gn]) * 0.125f;   // HD^-0.5 = 0.125
            qo[(size_t)((b * NHEAD + (gn >> 6)) * SEQ + n) * HD + (gn & 63)] = f2bf(q);
          } else if (gn < 2 * DIM) {
            int g2 = gn - DIM;
            ko[(size_t)((b * NHEAD + (g2 >> 6)) * SEQ + n) * HD + (g2 & 63)] = f2bf(val);
          } else {
            int g3 = gn - 2 * DIM;
            vto[(size_t)((b * NHEAD + (g3 >> 6)) * HD + (g3 & 63)) * SEQ + n] = f2bf(val + vbias[g3]);
          }
        } else if (MODE == 1) {
          outf[(size_t)gm * N + gn] = val + bias[gn] + resid[(size_t)gm * N + gn];
        } else if (MODE == 2) {
          float t = val + bias[gn];
          float g = 0.5f * t * (1.0f + erff(t * 0.70710678118f));
          outh[(size_t)gm * N + gn] = f2bf(g);
        } else {
          outf[(size_t)gm * N + gn] = val + bias[gn] + resid[(size_t)gm * N + gn];
        }
      }
    }
  }
}

// ---------------- flash attention: 4-wave blocks, K staged (dbuf), V direct (m169) ----------------
// 256 threads = 4 waves, 64 q-rows per block (16 per wave); grid 1024 -> 4 blocks/CU.
// S^T layout: lane holds q=lane&15, k = kt + j*16 + (lane>>4)*4 + r.
// K tile staged via glds (swizzled source, XOR read); V read direct (block-uniform, L1/L2-hot),
// issued a full softmax ahead of PV. T13 defer-max with first-tile guard.
__global__ __launch_bounds__(256)
void attn_kernel(const unsigned short* __restrict__ qg, const unsigned short* __restrict__ kg,
                 const unsigned short* __restrict__ vtg, const float* __restrict__ rpb,
                 const int* __restrict__ amask, unsigned short* __restrict__ outh)
{
  constexpr int PSTR = 72;
  __shared__ unsigned short smK[2][64 * 64];   // [key][d], swizzled; 8KB each
  __shared__ unsigned short pls[4][16 * PSTR]; // per-wave P tile
  const int tid = threadIdx.x;
  const int wv = tid >> 6, ln = tid & 63;
  const int bh = blockIdx.y, b = bh >> 4, h = bh & 15;
  const int q0 = blockIdx.x * 64 + wv * 16;
  const unsigned short* qb = qg  + (size_t)bh * SEQ * HD;
  const unsigned short* kb = kg  + (size_t)bh * SEQ * HD;
  const unsigned short* vb = vtg + (size_t)bh * HD * SEQ;
  const int* mp = amask + b * SEQ;
  unsigned short* myp = pls[wv];

  const int lcol = ln & 15, g = ln >> 4, lc8 = g * 8, lrow4 = g * 4;
  const int sw = (lcol & 7) << 3;              // read-side XOR (ushort units)
  const float* bprow = rpb + (size_t)h * SEQ * SEQ + (size_t)(q0 + lcol) * SEQ;

  const int srr = ln >> 3;                     // row within each 8-row stripe
  const int scc = (ln & 7) ^ srr;              // pre-swizzled global chunk

  bf16x8 aq0 = *reinterpret_cast<const bf16x8*>(qb + (size_t)(q0 + lcol) * HD + lc8);
  bf16x8 aq1 = *reinterpret_cast<const bf16x8*>(qb + (size_t)(q0 + lcol) * HD + 32 + lc8);

  f32x4 o[4] = {};
  float m = -1e30f, l = 0.f;

  auto stage = [&](int buf, int kt) {          // wave wv covers rows [wv*16, wv*16+16)
    int row = wv * 16 + srr;
    glds16(kb + (size_t)(kt + row) * HD + scc * 8,     &smK[buf][wv * 1024]);
    glds16(kb + (size_t)(kt + row + 8) * HD + scc * 8, &smK[buf][wv * 1024 + 512]);
  };

  stage(0, 0);
  __syncthreads();

  for (int t = 0; t < SEQ / 64; t++) {
    const int cur = t & 1;
    const int kt = t * 64;
    // bias + mask for this step (oldest in queue -> earliest wait)
    float4 bv4[4]; int4 mv[4];
#pragma unroll
    for (int j = 0; j < 4; j++) {
      bv4[j] = *reinterpret_cast<const float4*>(bprow + kt + j * 16 + lrow4);
      mv[j]  = *reinterpret_cast<const int4*>(mp + kt + j * 16 + lrow4);
    }
    if (t < SEQ / 64 - 1) stage(cur ^ 1, kt + 64);
    // V fragments direct from global (block-uniform tile, L1/L2-hot); used only at PV
    bf16x8 vf[2][4];
#pragma unroll
    for (int c = 0; c < 2; c++)
#pragma unroll
      for (int d = 0; d < 4; d++)
        vf[c][d] = *reinterpret_cast<const bf16x8*>(vb + (size_t)(d * 16 + lcol) * SEQ + kt + c * 32 + lc8);

    f32x4 s[4];
    __builtin_amdgcn_s_setprio(1);
#pragma unroll
    for (int j = 0; j < 4; j++) {
      int r = j * 16 + lcol;
      bf16x8 bk0 = *reinterpret_cast<const bf16x8*>(&smK[cur][r * 64 + (lc8 ^ sw)]);
      bf16x8 bk1 = *reinterpret_cast<const bf16x8*>(&smK[cur][r * 64 + ((32 + lc8) ^ sw)]);
      f32x4 z = {0.f, 0.f, 0.f, 0.f};
      z = __builtin_amdgcn_mfma_f32_16x16x32_bf16(bk0, aq0, z, 0, 0, 0);  // A=K, B=Q -> S^T
      z = __builtin_amdgcn_mfma_f32_16x16x32_bf16(bk1, aq1, z, 0, 0, 0);
      s[j] = z;
    }
    __builtin_amdgcn_s_setprio(0);
#pragma unroll
    for (int j = 0; j < 4; j++) {
      s[j][0] = mv[j].x ? s[j][0] + bv4[j].x : -1e30f;
      s[j][1] = mv[j].y ? s[j][1] + bv4[j].y : -1e30f;
      s[j][2] = mv[j].z ? s[j][2] + bv4[j].z : -1e30f;
      s[j][3] = mv[j].w ? s[j][3] + bv4[j].w : -1e30f;
    }
    float pm = fmaxf(fmaxf(fmaxf(s[0][0], s[0][1]), fmaxf(s[0][2], s[0][3])),
                     fmaxf(fmaxf(s[1][0], s[1][1]), fmaxf(s[1][2], s[1][3])));
    pm = fmaxf(pm, fmaxf(fmaxf(fmaxf(s[2][0], s[2][1]), fmaxf(s[2][2], s[2][3])),
                         fmaxf(fmaxf(s[3][0], s[3][1]), fmaxf(s[3][2], s[3][3]))));
    pm = fmaxf(pm, __shfl_xor(pm, 16));
    pm = fmaxf(pm, __shfl_xor(pm, 32));
    // T13 defer-max (guard: always rescale off the -1e30 init; skip only on small growth)
    if (m < -1e29f || !__all(pm - m <= 8.0f)) {
      float mn = fmaxf(m, pm);
      float fr = __expf(m - mn);
      m = mn;
      l *= fr;
      float frq[4];
#pragma unroll
      for (int r = 0; r < 4; r++) frq[r] = __shfl(fr, lrow4 + r);
#pragma unroll
      for (int d = 0; d < 4; d++)
#pragma unroll
        for (int r = 0; r < 4; r++) o[d][r] *= frq[r];
    }
    float rs = 0.f;
#pragma unroll
    for (int j = 0; j < 4; j++)
#pragma unroll
      for (int r = 0; r < 4; r++) {
        float p = __expf(s[j][r] - m);
        s[j][r] = p;
        rs += p;
      }
    rs += __shfl_xor(rs, 16);
    rs += __shfl_xor(rs, 32);
    l += rs;
    // P -> LDS [q][k] (packed 8B stores), read back as A-fragment (wave-private, in-order DS)
#pragma unroll
    for (int j = 0; j < 4; j++) {
      us4 po = { f2bf(s[j][0]), f2bf(s[j][1]), f2bf(s[j][2]), f2bf(s[j][3]) };
      *reinterpret_cast<us4*>(myp + lcol * PSTR + j * 16 + lrow4) = po;
    }
    asm volatile("s_waitcnt lgkmcnt(0)" ::: "memory");
    __builtin_amdgcn_sched_barrier(0);
    __builtin_amdgcn_s_setprio(1);
#pragma unroll
    for (int c = 0; c < 2; c++) {
      bf16x8 ap = *reinterpret_cast<const bf16x8*>(myp + lcol * PSTR + c * 32 + lc8);
#pragma unroll
      for (int d = 0; d < 4; d++)
        o[d] = __builtin_amdgcn_mfma_f32_16x16x32_bf16(ap, vf[c][d], o[d], 0, 0, 0);
    }
    __builtin_amdgcn_s_setprio(0);
    __syncthreads();   // drains K prefetch vmcnt; swaps buffers (4-wave barrier)
  }
  float linv = 1.0f / l;
  float lq[4];
#pragma unroll
  for (int r = 0; r < 4; r++) lq[r] = __shfl(linv, lrow4 + r);
#pragma unroll
  for (int d = 0; d < 4; d++)
#pragma unroll
    for (int r = 0; r < 4; r++)
      outh[(size_t)(b * SEQ + q0 + lrow4 + r) * DIM + h * HD + d * 16 + lcol] = f2bf(o[d][r] * lq[r]);
}

// ---------------- host ----------------
extern "C" void kernel_launch(void* const* d_in, const int* in_sizes, int n_in,
                              void* d_out, int out_size, void* d_ws, size_t ws_size,
                              hipStream_t stream)
{
  const float* x      = (const float*)d_in[0];
  const float* rpb    = (const float*)d_in[1];
  const int*   amask  = (const int*)d_in[2];
  const float* n1w    = (const float*)d_in[3];
  const float* n1b    = (const float*)d_in[4];
  const float* qkv_w  = (const float*)d_in[5];
  const float* q_bias = (const float*)d_in[6];
  const float* v_bias = (const float*)d_in[7];
  const float* proj_w = (const float*)d_in[8];
  const float* proj_b = (const float*)d_in[9];
  const float* n2w    = (const float*)d_in[10];
  const float* n2b    = (const float*)d_in[11];
  const float* w1     = (const float*)d_in[12];
  const float* b1     = (const float*)d_in[13];
  const float* w2     = (const float*)d_in[14];
  const float* b2     = (const float*)d_in[15];
  float* out = (float*)d_out;

  char* ws = (char*)d_ws;
  size_t off = 0;
  auto alloc = [&](size_t bytes) { char* p = ws + off; off += (bytes + 255) & ~(size_t)255; return p; };
  unsigned short* xn1    = (unsigned short*)alloc((size_t)ROWS * DIM * 2);
  unsigned short* xn2    = (unsigned short*)alloc((size_t)ROWS * DIM * 2);
  unsigned short* wqkv_h = (unsigned short*)alloc((size_t)3 * DIM * DIM * 2);
  unsigned short* wproj_h= (unsigned short*)alloc((size_t)DIM * DIM * 2);
  unsigned short* w1_h   = (unsigned short*)alloc((size_t)HIDDEN * DIM * 2);
  unsigned short* w2_h   = (unsigned short*)alloc((size_t)DIM * HIDDEN * 2);
  unsigned short* qh     = (unsigned short*)alloc((size_t)ROWS * DIM * 2);
  unsigned short* kh     = (unsigned short*)alloc((size_t)ROWS * DIM * 2);
  unsigned short* vth    = (unsigned short*)alloc((size_t)ROWS * DIM * 2);
  unsigned short* attn_h = (unsigned short*)alloc((size_t)ROWS * DIM * 2);
  float*          xres   = (float*)alloc((size_t)ROWS * DIM * 4);
  unsigned short* hmid   = (unsigned short*)alloc((size_t)ROWS * HIDDEN * 2);

  // all weight conversions in one launch
  cvt_all<<<2048, 256, 0, stream>>>(qkv_w, proj_w, w1, w2, wqkv_h, wproj_h, w1_h, w2_h);

  // LN1
  ln_kernel<<<ROWS, 256, 0, stream>>>(x, n1w, n1b, xn1);
  // QKV GEMM (M=4096, N=3072, K=1024) -- 768 blocks
  gemm128<0, 128><<<dim3(ROWS / 128, 3 * DIM / 128), 256, 0, stream>>>(
      xn1, wqkv_h, DIM, 3 * DIM, nullptr, nullptr, nullptr, nullptr, qh, kh, vth, q_bias, v_bias);
  // attention -- 1024 blocks x 256 threads (4 waves)
  attn_kernel<<<dim3(SEQ / 64, BATCH * NHEAD), 256, 0, stream>>>(qh, kh, vth, rpb, amask, attn_h);
  // proj GEMM + residual -> x_res (fp32) -- BN=64 -> 512 blocks
  gemm128<1, 64><<<dim3(ROWS / 128, DIM / 64), 256, 0, stream>>>(
      attn_h, wproj_h, DIM, DIM, proj_b, x, xres, nullptr, nullptr, nullptr, nullptr, nullptr, nullptr);
  // LN2
  ln_kernel<<<ROWS, 256, 0, stream>>>(xres, n2w, n2b, xn2);
  // MLP1 + GELU -- 1024 blocks
  gemm128<2, 128><<<dim3(ROWS / 128, HIDDEN / 128), 256, 0, stream>>>(
      xn2, w1_h, DIM, HIDDEN, b1, nullptr, nullptr, hmid, nullptr, nullptr, nullptr, nullptr, nullptr);
  // MLP2 + residual -> out -- BN=64 -> 512 blocks
  gemm128<3, 64><<<dim3(ROWS / 128, DIM / 64), 256, 0, stream>>>(
      hmid, w2_h, HIDDEN, DIM, b2, xres, out, nullptr, nullptr, nullptr, nullptr, nullptr, nullptr);
}

// Round 9
// 307.574 us; speedup vs baseline: 1.2780x; 1.2069x over previous
//
#include <hip/hip_runtime.h>
#include <math.h>

#define DIM 1024
#define NHEAD 16
#define HD 64
#define HIDDEN 4096
#define SEQ 1024
#define BATCH 4
#define ROWS (BATCH*SEQ)   // 4096 tokens

typedef __attribute__((ext_vector_type(8))) short bf16x8;
typedef __attribute__((ext_vector_type(4))) float f32x4;
typedef __attribute__((ext_vector_type(4))) unsigned short us4;

__device__ __forceinline__ unsigned short f2bf(float f) {
  unsigned u = __builtin_bit_cast(unsigned, f);
  u += 0x7fffu + ((u >> 16) & 1u);           // round-to-nearest-even
  return (unsigned short)(u >> 16);
}

__device__ __forceinline__ void glds16(const void* g, void* l) {
  __builtin_amdgcn_global_load_lds((const __attribute__((address_space(1))) void*)g,
                                   (__attribute__((address_space(3))) void*)l,
                                   16, 0, 0);
}

// ---------------- fp32 -> bf16 weight conversion (all 4 weights, one launch) ----------------
__global__ void cvt_all(const float* __restrict__ a, const float* __restrict__ b,
                        const float* __restrict__ c, const float* __restrict__ d,
                        unsigned short* __restrict__ oa, unsigned short* __restrict__ ob,
                        unsigned short* __restrict__ oc, unsigned short* __restrict__ od) {
  const int na = 3 * DIM * DIM / 4, nb = DIM * DIM / 4, nc = HIDDEN * DIM / 4, nd = DIM * HIDDEN / 4;
  const int total = na + nb + nc + nd;
  for (int i = blockIdx.x * blockDim.x + threadIdx.x; i < total; i += gridDim.x * blockDim.x) {
    const float* in; unsigned short* out; int j = i;
    if (j < na)             { in = a; out = oa; }
    else if ((j -= na) < nb){ in = b; out = ob; }
    else if ((j -= nb) < nc){ in = c; out = oc; }
    else                    { j -= nc; in = d; out = od; }
    float4 v = reinterpret_cast<const float4*>(in)[j];
    us4 o = { f2bf(v.x), f2bf(v.y), f2bf(v.z), f2bf(v.w) };
    reinterpret_cast<us4*>(out)[j] = o;
  }
}

// ---------------- LayerNorm: fp32 row -> bf16 normalized ----------------
__global__ void ln_kernel(const float* __restrict__ x, const float* __restrict__ w,
                          const float* __restrict__ b, unsigned short* __restrict__ out) {
  int row = blockIdx.x;
  const float* xr = x + (size_t)row * DIM;
  int t = threadIdx.x;
  float4 v = *reinterpret_cast<const float4*>(xr + t * 4);
  float s  = v.x + v.y + v.z + v.w;
  float s2 = v.x*v.x + v.y*v.y + v.z*v.z + v.w*v.w;
#pragma unroll
  for (int m = 1; m < 64; m <<= 1) { s += __shfl_xor(s, m); s2 += __shfl_xor(s2, m); }
  __shared__ float red[8];
  int wv = t >> 6, ln = t & 63;
  if (ln == 0) { red[wv] = s; red[4 + wv] = s2; }
  __syncthreads();
  s  = red[0] + red[1] + red[2] + red[3];
  s2 = red[4] + red[5] + red[6] + red[7];
  float mu  = s * (1.0f / DIM);
  float var = s2 * (1.0f / DIM) - mu * mu;
  float rs  = rsqrtf(var + 1e-5f);
  float4 wv4 = *reinterpret_cast<const float4*>(w + t * 4);
  float4 bv4 = *reinterpret_cast<const float4*>(b + t * 4);
  us4 o = { f2bf((v.x - mu) * rs * wv4.x + bv4.x),
            f2bf((v.y - mu) * rs * wv4.y + bv4.y),
            f2bf((v.z - mu) * rs * wv4.z + bv4.z),
            f2bf((v.w - mu) * rs * wv4.w + bv4.w) };
  *reinterpret_cast<us4*>(out + (size_t)row * DIM + t * 4) = o;
}

// ---------------- 128xBN bf16 NT GEMM, 2-phase double-buffered (R5 proven), fused epilogues ----------------
// MODE 0: QKV  -> writes q (bias+scale), k, vT   (bf16)
// MODE 1: proj -> outf = acc + bias + resid      (fp32, = x_res)
// MODE 2: mlp1 -> outh = gelu(acc + bias)        (bf16)
// MODE 3: mlp2 -> outf = acc + bias + resid      (fp32, = final out)
template<int MODE, int BN>
__global__ __launch_bounds__(256)
void gemm128(const unsigned short* __restrict__ A, const unsigned short* __restrict__ Bw,
             int K, int N,
             const float* __restrict__ bias, const float* __restrict__ resid,
             float* __restrict__ outf, unsigned short* __restrict__ outh,
             unsigned short* __restrict__ qo, unsigned short* __restrict__ ko,
             unsigned short* __restrict__ vto,
             const float* __restrict__ qbias, const float* __restrict__ vbias)
{
  constexpr int NJ = BN / 32;                 // B-frags per wave
  __shared__ unsigned short smA[2][128 * 32];
  __shared__ unsigned short smB[2][BN * 32];
  const int tid = threadIdx.x;
  const int wv = tid >> 6, ln = tid & 63;
  const int tile_m = blockIdx.x * 128, tile_n = blockIdx.y * BN;
  const int wm = (wv >> 1) * 64, wn = (wv & 1) * (BN / 2);

  const unsigned short* gA = A  + (size_t)(tile_m + wv * 32 + (ln >> 2)) * K + (ln & 3) * 8;
  const unsigned short* gB = Bw + (size_t)(tile_n + wv * (BN / 4) + (ln >> 2)) * K + (ln & 3) * 8;

  f32x4 acc[4][NJ] = {};
  const int lr = ln & 15, lc8 = (ln >> 4) * 8;

  auto stage = [&](int buf, int k0) {
    glds16(gA + k0,                  &smA[buf][wv * 1024]);
    glds16(gA + k0 + 16 * (size_t)K, &smA[buf][wv * 1024 + 512]);
    glds16(gB + k0,                  &smB[buf][wv * (BN / 4) * 32]);
    if (BN == 128) glds16(gB + k0 + 16 * (size_t)K, &smB[buf][wv * 1024 + 512]);
  };

  stage(0, 0);
  __syncthreads();                 // prologue drain (one-time full vmcnt wait)
  int cur = 0;
  for (int k0 = 0; k0 < K; k0 += 32) {
    if (k0 + 32 < K) stage(cur ^ 1, k0 + 32);   // issue next tile FIRST
    bf16x8 af[4], bfr[NJ];
#pragma unroll
    for (int i = 0; i < 4; i++)
      af[i] = *reinterpret_cast<const bf16x8*>(&smA[cur][(wm + i * 16 + lr) * 32 + lc8]);
#pragma unroll
    for (int j = 0; j < NJ; j++)
      bfr[j] = *reinterpret_cast<const bf16x8*>(&smB[cur][(wn + j * 16 + lr) * 32 + lc8]);
#pragma unroll
    for (int i = 0; i < 4; i++)
#pragma unroll
      for (int j = 0; j < NJ; j++)
        acc[i][j] = __builtin_amdgcn_mfma_f32_16x16x32_bf16(af[i], bfr[j], acc[i][j], 0, 0, 0);
    __syncthreads();               // drains the prefetch issued above + barrier
    cur ^= 1;
  }

  const int lcol = ln & 15, lrow4 = (ln >> 4) * 4;
#pragma unroll
  for (int i = 0; i < 4; i++) {
#pragma unroll
    for (int j = 0; j < NJ; j++) {
      int gm0 = tile_m + wm + i * 16 + lrow4;
      int gn  = tile_n + wn + j * 16 + lcol;
#pragma unroll
      for (int r = 0; r < 4; r++) {
        int gm = gm0 + r;
        float val = acc[i][j][r];
        if (MODE == 0) {
          int b = gm >> 10, n = gm & 1023;
          if (gn < DIM) {
            float q = (val + qbias[gn]) * 0.125f;   // HD^-0.5 = 0.125
            qo[(size_t)((b * NHEAD + (gn >> 6)) * SEQ + n) * HD + (gn & 63)] = f2bf(q);
          } else if (gn < 2 * DIM) {
            int g2 = gn - DIM;
            ko[(size_t)((b * NHEAD + (g2 >> 6)) * SEQ + n) * HD + (g2 & 63)] = f2bf(val);
          } else {
            int g3 = gn - 2 * DIM;
            vto[(size_t)((b * NHEAD + (g3 >> 6)) * HD + (g3 & 63)) * SEQ + n] = f2bf(val + vbias[g3]);
          }
        } else if (MODE == 1) {
          outf[(size_t)gm * N + gn] = val + bias[gn] + resid[(size_t)gm * N + gn];
        } else if (MODE == 2) {
          float t = val + bias[gn];
          float g = 0.5f * t * (1.0f + erff(t * 0.70710678118f));
          outh[(size_t)gm * N + gn] = f2bf(g);
        } else {
          outf[(size_t)gm * N + gn] = val + bias[gn] + resid[(size_t)gm * N + gn];
        }
      }
    }
  }
}

// ---------------- flash attention (R5 schedule, XCD-local grid) ----------------
// 512 threads = 8 waves, 128 q-rows per block (16 per wave), k-blocks of 64.
// Grid transposed: bh = blockIdx.x, q-block = blockIdx.y -> linear id = bh + 64*qb,
// XCD = bh%8 = h%8: all q-blocks of a head AND all 4 batches of that head pin to one
// XCD -> K/V fetched once per XCD (not 8x), rpb[h] reused by 4 batches (T1 mechanism).
// S^T layout: lane holds q=lane&15, k = kt + j*16 + (lane>>4)*4 + r.
// T13 defer-max: skip O-rescale while __all(pm - m <= 8) (guarded on first tile).
__global__ __launch_bounds__(512)
void attn_kernel(const unsigned short* __restrict__ qg, const unsigned short* __restrict__ kg,
                 const unsigned short* __restrict__ vtg, const float* __restrict__ rpb,
                 const int* __restrict__ amask, unsigned short* __restrict__ outh)
{
  constexpr int PSTR = 72;
  __shared__ unsigned short smK[2][64 * 64];   // [key][d], swizzled
  __shared__ unsigned short smV[2][64 * 64];   // [d][key], swizzled
  __shared__ unsigned short pls[8][16 * PSTR]; // per-wave P tile
  const int tid = threadIdx.x;
  const int wv = tid >> 6, ln = tid & 63;
  const int bh = blockIdx.x, b = bh >> 4, h = bh & 15;
  const int q0 = blockIdx.y * 128 + wv * 16;
  const unsigned short* qb = qg  + (size_t)bh * SEQ * HD;
  const unsigned short* kb = kg  + (size_t)bh * SEQ * HD;
  const unsigned short* vb = vtg + (size_t)bh * HD * SEQ;
  const int* mp = amask + b * SEQ;
  unsigned short* myp = pls[wv];

  const int lcol = ln & 15, g = ln >> 4, lc8 = g * 8, lrow4 = g * 4;
  const int sw = (lcol & 7) << 3;              // read-side XOR (ushort units)
  const float* bprow = rpb + (size_t)h * SEQ * SEQ + (size_t)(q0 + lcol) * SEQ;

  const int srr = ln >> 3;                     // row within the 8-row chunk
  const int scc = (ln & 7) ^ srr;              // pre-swizzled global 8-ushort chunk

  bf16x8 aq0 = *reinterpret_cast<const bf16x8*>(qb + (size_t)(q0 + lcol) * HD + lc8);
  bf16x8 aq1 = *reinterpret_cast<const bf16x8*>(qb + (size_t)(q0 + lcol) * HD + 32 + lc8);

  f32x4 o[4] = {};
  float m = -1e30f, l = 0.f;

  auto stage = [&](int buf, int kt) {
    int row = wv * 8 + srr;
    glds16(kb + (size_t)(kt + row) * HD + scc * 8, &smK[buf][wv * 512]);
    glds16(vb + (size_t)row * SEQ + kt + scc * 8, &smV[buf][wv * 512]);
  };

  stage(0, 0);
  __syncthreads();

  for (int t = 0; t < SEQ / 64; t++) {
    const int cur = t & 1;
    const int kt = t * 64;
    // bias + mask loads FIRST (so their waitcnt doesn't drain the tile prefetch)
    float4 bv4[4]; int4 mv[4];
#pragma unroll
    for (int j = 0; j < 4; j++) {
      bv4[j] = *reinterpret_cast<const float4*>(bprow + kt + j * 16 + lrow4);
      mv[j]  = *reinterpret_cast<const int4*>(mp + kt + j * 16 + lrow4);
    }
    if (t < SEQ / 64 - 1) stage(cur ^ 1, kt + 64);

    f32x4 s[4];
#pragma unroll
    for (int j = 0; j < 4; j++) {
      int r = j * 16 + lcol;
      bf16x8 bk0 = *reinterpret_cast<const bf16x8*>(&smK[cur][r * 64 + (lc8 ^ sw)]);
      bf16x8 bk1 = *reinterpret_cast<const bf16x8*>(&smK[cur][r * 64 + ((32 + lc8) ^ sw)]);
      f32x4 z = {0.f, 0.f, 0.f, 0.f};
      z = __builtin_amdgcn_mfma_f32_16x16x32_bf16(bk0, aq0, z, 0, 0, 0);  // A=K, B=Q -> S^T
      z = __builtin_amdgcn_mfma_f32_16x16x32_bf16(bk1, aq1, z, 0, 0, 0);
      s[j] = z;
    }
#pragma unroll
    for (int j = 0; j < 4; j++) {
      s[j][0] = mv[j].x ? s[j][0] + bv4[j].x : -1e30f;
      s[j][1] = mv[j].y ? s[j][1] + bv4[j].y : -1e30f;
      s[j][2] = mv[j].z ? s[j][2] + bv4[j].z : -1e30f;
      s[j][3] = mv[j].w ? s[j][3] + bv4[j].w : -1e30f;
    }
    float pm = fmaxf(fmaxf(fmaxf(s[0][0], s[0][1]), fmaxf(s[0][2], s[0][3])),
                     fmaxf(fmaxf(s[1][0], s[1][1]), fmaxf(s[1][2], s[1][3])));
    pm = fmaxf(pm, fmaxf(fmaxf(fmaxf(s[2][0], s[2][1]), fmaxf(s[2][2], s[2][3])),
                         fmaxf(fmaxf(s[3][0], s[3][1]), fmaxf(s[3][2], s[3][3]))));
    pm = fmaxf(pm, __shfl_xor(pm, 16));
    pm = fmaxf(pm, __shfl_xor(pm, 32));
    // T13 defer-max (first-tile guard): rescale only on real max growth
    if (m < -1e29f || !__all(pm - m <= 8.0f)) {
      float mn = fmaxf(m, pm);
      float fr = __expf(m - mn);
      m = mn;
      l *= fr;
      float frq[4];
#pragma unroll
      for (int r = 0; r < 4; r++) frq[r] = __shfl(fr, lrow4 + r);
#pragma unroll
      for (int d = 0; d < 4; d++)
#pragma unroll
        for (int r = 0; r < 4; r++) o[d][r] *= frq[r];
    }
    float rs = 0.f;
#pragma unroll
    for (int j = 0; j < 4; j++)
#pragma unroll
      for (int r = 0; r < 4; r++) {
        float p = __expf(s[j][r] - m);
        s[j][r] = p;
        rs += p;
      }
    rs += __shfl_xor(rs, 16);
    rs += __shfl_xor(rs, 32);
    l += rs;
    // P -> LDS [q][k] (packed 8B stores), read back as A-fragment
#pragma unroll
    for (int j = 0; j < 4; j++) {
      us4 po = { f2bf(s[j][0]), f2bf(s[j][1]), f2bf(s[j][2]), f2bf(s[j][3]) };
      *reinterpret_cast<us4*>(myp + lcol * PSTR + j * 16 + lrow4) = po;
    }
    asm volatile("s_waitcnt lgkmcnt(0)" ::: "memory");
    __builtin_amdgcn_sched_barrier(0);
#pragma unroll
    for (int c = 0; c < 2; c++) {
      bf16x8 ap = *reinterpret_cast<const bf16x8*>(myp + lcol * PSTR + c * 32 + lc8);
#pragma unroll
      for (int d = 0; d < 4; d++) {
        int vr = d * 16 + lcol;
        bf16x8 bvv = *reinterpret_cast<const bf16x8*>(&smV[cur][vr * 64 + ((c * 32 + lc8) ^ sw)]);
        o[d] = __builtin_amdgcn_mfma_f32_16x16x32_bf16(ap, bvv, o[d], 0, 0, 0);
      }
    }
    __syncthreads();   // drains prefetch vmcnt + P-LDS; swaps buffers
  }
  float linv = 1.0f / l;
  float lq[4];
#pragma unroll
  for (int r = 0; r < 4; r++) lq[r] = __shfl(linv, lrow4 + r);
#pragma unroll
  for (int d = 0; d < 4; d++)
#pragma unroll
    for (int r = 0; r < 4; r++)
      outh[(size_t)(b * SEQ + q0 + lrow4 + r) * DIM + h * HD + d * 16 + lcol] = f2bf(o[d][r] * lq[r]);
}

// ---------------- host ----------------
extern "C" void kernel_launch(void* const* d_in, const int* in_sizes, int n_in,
                              void* d_out, int out_size, void* d_ws, size_t ws_size,
                              hipStream_t stream)
{
  const float* x      = (const float*)d_in[0];
  const float* rpb    = (const float*)d_in[1];
  const int*   amask  = (const int*)d_in[2];
  const float* n1w    = (const float*)d_in[3];
  const float* n1b    = (const float*)d_in[4];
  const float* qkv_w  = (const float*)d_in[5];
  const float* q_bias = (const float*)d_in[6];
  const float* v_bias = (const float*)d_in[7];
  const float* proj_w = (const float*)d_in[8];
  const float* proj_b = (const float*)d_in[9];
  const float* n2w    = (const float*)d_in[10];
  const float* n2b    = (const float*)d_in[11];
  const float* w1     = (const float*)d_in[12];
  const float* b1     = (const float*)d_in[13];
  const float* w2     = (const float*)d_in[14];
  const float* b2     = (const float*)d_in[15];
  float* out = (float*)d_out;

  char* ws = (char*)d_ws;
  size_t off = 0;
  auto alloc = [&](size_t bytes) { char* p = ws + off; off += (bytes + 255) & ~(size_t)255; return p; };
  unsigned short* xn1    = (unsigned short*)alloc((size_t)ROWS * DIM * 2);
  unsigned short* xn2    = (unsigned short*)alloc((size_t)ROWS * DIM * 2);
  unsigned short* wqkv_h = (unsigned short*)alloc((size_t)3 * DIM * DIM * 2);
  unsigned short* wproj_h= (unsigned short*)alloc((size_t)DIM * DIM * 2);
  unsigned short* w1_h   = (unsigned short*)alloc((size_t)HIDDEN * DIM * 2);
  unsigned short* w2_h   = (unsigned short*)alloc((size_t)DIM * HIDDEN * 2);
  unsigned short* qh     = (unsigned short*)alloc((size_t)ROWS * DIM * 2);
  unsigned short* kh     = (unsigned short*)alloc((size_t)ROWS * DIM * 2);
  unsigned short* vth    = (unsigned short*)alloc((size_t)ROWS * DIM * 2);
  unsigned short* attn_h = (unsigned short*)alloc((size_t)ROWS * DIM * 2);
  float*          xres   = (float*)alloc((size_t)ROWS * DIM * 4);
  unsigned short* hmid   = (unsigned short*)alloc((size_t)ROWS * HIDDEN * 2);

  // all weight conversions in one launch
  cvt_all<<<2048, 256, 0, stream>>>(qkv_w, proj_w, w1, w2, wqkv_h, wproj_h, w1_h, w2_h);

  // LN1
  ln_kernel<<<ROWS, 256, 0, stream>>>(x, n1w, n1b, xn1);
  // QKV GEMM (M=4096, N=3072, K=1024) -- 768 blocks
  gemm128<0, 128><<<dim3(ROWS / 128, 3 * DIM / 128), 256, 0, stream>>>(
      xn1, wqkv_h, DIM, 3 * DIM, nullptr, nullptr, nullptr, nullptr, qh, kh, vth, q_bias, v_bias);
  // attention -- grid (bh, qblock): XCD = bh%8 -> per-head K/V/rpb locality
  attn_kernel<<<dim3(BATCH * NHEAD, SEQ / 128), 512, 0, stream>>>(qh, kh, vth, rpb, amask, attn_h);
  // proj GEMM + residual -> x_res (fp32) -- BN=64 -> 512 blocks
  gemm128<1, 64><<<dim3(ROWS / 128, DIM / 64), 256, 0, stream>>>(
      attn_h, wproj_h, DIM, DIM, proj_b, x, xres, nullptr, nullptr, nullptr, nullptr, nullptr, nullptr);
  // LN2
  ln_kernel<<<ROWS, 256, 0, stream>>>(xres, n2w, n2b, xn2);
  // MLP1 + GELU -- 1024 blocks
  gemm128<2, 128><<<dim3(ROWS / 128, HIDDEN / 128), 256, 0, stream>>>(
      xn2, w1_h, DIM, HIDDEN, b1, nullptr, nullptr, hmid, nullptr, nullptr, nullptr, nullptr, nullptr);
  // MLP2 + residual -> out -- BN=64 -> 512 blocks
  gemm128<3, 64><<<dim3(ROWS / 128, DIM / 64), 256, 0, stream>>>(
      hmid, w2_h, HIDDEN, DIM, b2, xres, out, nullptr, nullptr, nullptr, nullptr, nullptr, nullptr);
}

// Round 10
// 304.470 us; speedup vs baseline: 1.2910x; 1.0102x over previous
//
#include <hip/hip_runtime.h>
#include <math.h>

#define DIM 1024
#define NHEAD 16
#define HD 64
#define HIDDEN 4096
#define SEQ 1024
#define BATCH 4
#define ROWS (BATCH*SEQ)   // 4096 tokens

typedef __attribute__((ext_vector_type(8))) short bf16x8;
typedef __attribute__((ext_vector_type(4))) float f32x4;
typedef __attribute__((ext_vector_type(4))) unsigned short us4;

__device__ __forceinline__ unsigned short f2bf(float f) {
  unsigned u = __builtin_bit_cast(unsigned, f);
  u += 0x7fffu + ((u >> 16) & 1u);           // round-to-nearest-even
  return (unsigned short)(u >> 16);
}

__device__ __forceinline__ void glds16(const void* g, void* l) {
  __builtin_amdgcn_global_load_lds((const __attribute__((address_space(1))) void*)g,
                                   (__attribute__((address_space(3))) void*)l,
                                   16, 0, 0);
}

// ---------------- fp32 -> bf16 weight conversion (all 4 weights, one launch) ----------------
__global__ void cvt_all(const float* __restrict__ a, const float* __restrict__ b,
                        const float* __restrict__ c, const float* __restrict__ d,
                        unsigned short* __restrict__ oa, unsigned short* __restrict__ ob,
                        unsigned short* __restrict__ oc, unsigned short* __restrict__ od) {
  const int na = 3 * DIM * DIM / 4, nb = DIM * DIM / 4, nc = HIDDEN * DIM / 4, nd = DIM * HIDDEN / 4;
  const int total = na + nb + nc + nd;
  for (int i = blockIdx.x * blockDim.x + threadIdx.x; i < total; i += gridDim.x * blockDim.x) {
    const float* in; unsigned short* out; int j = i;
    if (j < na)             { in = a; out = oa; }
    else if ((j -= na) < nb){ in = b; out = ob; }
    else if ((j -= nb) < nc){ in = c; out = oc; }
    else                    { j -= nc; in = d; out = od; }
    float4 v = reinterpret_cast<const float4*>(in)[j];
    us4 o = { f2bf(v.x), f2bf(v.y), f2bf(v.z), f2bf(v.w) };
    reinterpret_cast<us4*>(out)[j] = o;
  }
}

// ---------------- LayerNorm: fp32 row -> bf16 normalized ----------------
__global__ void ln_kernel(const float* __restrict__ x, const float* __restrict__ w,
                          const float* __restrict__ b, unsigned short* __restrict__ out) {
  int row = blockIdx.x;
  const float* xr = x + (size_t)row * DIM;
  int t = threadIdx.x;
  float4 v = *reinterpret_cast<const float4*>(xr + t * 4);
  float s  = v.x + v.y + v.z + v.w;
  float s2 = v.x*v.x + v.y*v.y + v.z*v.z + v.w*v.w;
#pragma unroll
  for (int m = 1; m < 64; m <<= 1) { s += __shfl_xor(s, m); s2 += __shfl_xor(s2, m); }
  __shared__ float red[8];
  int wv = t >> 6, ln = t & 63;
  if (ln == 0) { red[wv] = s; red[4 + wv] = s2; }
  __syncthreads();
  s  = red[0] + red[1] + red[2] + red[3];
  s2 = red[4] + red[5] + red[6] + red[7];
  float mu  = s * (1.0f / DIM);
  float var = s2 * (1.0f / DIM) - mu * mu;
  float rs  = rsqrtf(var + 1e-5f);
  float4 wv4 = *reinterpret_cast<const float4*>(w + t * 4);
  float4 bv4 = *reinterpret_cast<const float4*>(b + t * 4);
  us4 o = { f2bf((v.x - mu) * rs * wv4.x + bv4.x),
            f2bf((v.y - mu) * rs * wv4.y + bv4.y),
            f2bf((v.z - mu) * rs * wv4.z + bv4.z),
            f2bf((v.w - mu) * rs * wv4.w + bv4.w) };
  *reinterpret_cast<us4*>(out + (size_t)row * DIM + t * 4) = o;
}

// ---------------- 128xBN bf16 NT GEMM, 2-phase dbuf + T2 XOR-swizzled LDS ----------------
// Bank-conflict fix (rule #21: both-sides-or-neither with global_load_lds):
//   [row][32] ushort tile has 64B row stride -> ds_read_b128 at fixed chunk was 8-way.
//   chunk' = chunk ^ ((row>>1)&3) spreads 16 rows over all 8 (parity x chunk) 16B slots
//   exactly twice -> 2-way = free (m136). Staging pre-swizzles the GLOBAL source chunk
//   (LDS dest stays linear as glds16 requires); reads XOR the chunk the same way.
//   Read-side XOR is lane-constant: all row bases are multiples of 16.
// MODE 0: QKV  -> writes q (bias+scale), k, vT   (bf16)
// MODE 1: proj -> outf = acc + bias + resid      (fp32, = x_res)
// MODE 2: mlp1 -> outh = gelu(acc + bias)        (bf16)
// MODE 3: mlp2 -> outf = acc + bias + resid      (fp32, = final out)
template<int MODE, int BN>
__global__ __launch_bounds__(256)
void gemm128(const unsigned short* __restrict__ A, const unsigned short* __restrict__ Bw,
             int K, int N,
             const float* __restrict__ bias, const float* __restrict__ resid,
             float* __restrict__ outf, unsigned short* __restrict__ outh,
             unsigned short* __restrict__ qo, unsigned short* __restrict__ ko,
             unsigned short* __restrict__ vto,
             const float* __restrict__ qbias, const float* __restrict__ vbias)
{
  constexpr int NJ = BN / 32;                 // B-frags per wave
  __shared__ unsigned short smA[2][128 * 32];
  __shared__ unsigned short smB[2][BN * 32];
  const int tid = threadIdx.x;
  const int wv = tid >> 6, ln = tid & 63;
  const int tile_m = blockIdx.x * 128, tile_n = blockIdx.y * BN;
  const int wm = (wv >> 1) * 64, wn = (wv & 1) * (BN / 2);

  const int srow   = ln >> 2;                              // staging row within 16-row chunk
  const int schunk = (ln & 3) ^ ((srow >> 1) & 3);         // pre-swizzled global chunk
  const unsigned short* gA = A  + (size_t)(tile_m + wv * 32 + srow) * K + schunk * 8;
  const unsigned short* gB = Bw + (size_t)(tile_n + wv * (BN / 4) + srow) * K + schunk * 8;

  f32x4 acc[4][NJ] = {};
  const int lr = ln & 15, lc8 = (ln >> 4) * 8;
  const int gxor = ((lr >> 1) & 3) << 3;                   // read-side XOR (ushort units)

  auto stage = [&](int buf, int k0) {
    glds16(gA + k0,                  &smA[buf][wv * 1024]);
    glds16(gA + k0 + 16 * (size_t)K, &smA[buf][wv * 1024 + 512]);  // rows+16: same swizzle (16>>1 ≡ 0 mod 4)
    glds16(gB + k0,                  &smB[buf][wv * (BN / 4) * 32]);
    if (BN == 128) glds16(gB + k0 + 16 * (size_t)K, &smB[buf][wv * 1024 + 512]);
  };

  stage(0, 0);
  __syncthreads();                 // prologue drain (one-time full vmcnt wait)
  int cur = 0;
  for (int k0 = 0; k0 < K; k0 += 32) {
    if (k0 + 32 < K) stage(cur ^ 1, k0 + 32);   // issue next tile FIRST
    bf16x8 af[4], bfr[NJ];
#pragma unroll
    for (int i = 0; i < 4; i++)
      af[i] = *reinterpret_cast<const bf16x8*>(&smA[cur][(wm + i * 16 + lr) * 32 + (lc8 ^ gxor)]);
#pragma unroll
    for (int j = 0; j < NJ; j++)
      bfr[j] = *reinterpret_cast<const bf16x8*>(&smB[cur][(wn + j * 16 + lr) * 32 + (lc8 ^ gxor)]);
#pragma unroll
    for (int i = 0; i < 4; i++)
#pragma unroll
      for (int j = 0; j < NJ; j++)
        acc[i][j] = __builtin_amdgcn_mfma_f32_16x16x32_bf16(af[i], bfr[j], acc[i][j], 0, 0, 0);
    __syncthreads();               // drains the prefetch issued above + barrier
    cur ^= 1;
  }

  const int lcol = ln & 15, lrow4 = (ln >> 4) * 4;
#pragma unroll
  for (int i = 0; i < 4; i++) {
#pragma unroll
    for (int j = 0; j < NJ; j++) {
      int gm0 = tile_m + wm + i * 16 + lrow4;
      int gn  = tile_n + wn + j * 16 + lcol;
#pragma unroll
      for (int r = 0; r < 4; r++) {
        int gm = gm0 + r;
        float val = acc[i][j][r];
        if (MODE == 0) {
          int b = gm >> 10, n = gm & 1023;
          if (gn < DIM) {
            float q = (val + qbias[gn]) * 0.125f;   // HD^-0.5 = 0.125
            qo[(size_t)((b * NHEAD + (gn >> 6)) * SEQ + n) * HD + (gn & 63)] = f2bf(q);
          } else if (gn < 2 * DIM) {
            int g2 = gn - DIM;
            ko[(size_t)((b * NHEAD + (g2 >> 6)) * SEQ + n) * HD + (g2 & 63)] = f2bf(val);
          } else {
            int g3 = gn - 2 * DIM;
            vto[(size_t)((b * NHEAD + (g3 >> 6)) * HD + (g3 & 63)) * SEQ + n] = f2bf(val + vbias[g3]);
          }
        } else if (MODE == 1) {
          outf[(size_t)gm * N + gn] = val + bias[gn] + resid[(size_t)gm * N + gn];
        } else if (MODE == 2) {
          float t = val + bias[gn];
          float g = 0.5f * t * (1.0f + erff(t * 0.70710678118f));
          outh[(size_t)gm * N + gn] = f2bf(g);
        } else {
          outf[(size_t)gm * N + gn] = val + bias[gn] + resid[(size_t)gm * N + gn];
        }
      }
    }
  }
}

// ---------------- flash attention (R5 schedule, XCD-local grid) -- R9 proven ----------------
__global__ __launch_bounds__(512)
void attn_kernel(const unsigned short* __restrict__ qg, const unsigned short* __restrict__ kg,
                 const unsigned short* __restrict__ vtg, const float* __restrict__ rpb,
                 const int* __restrict__ amask, unsigned short* __restrict__ outh)
{
  constexpr int PSTR = 72;
  __shared__ unsigned short smK[2][64 * 64];   // [key][d], swizzled
  __shared__ unsigned short smV[2][64 * 64];   // [d][key], swizzled
  __shared__ unsigned short pls[8][16 * PSTR]; // per-wave P tile
  const int tid = threadIdx.x;
  const int wv = tid >> 6, ln = tid & 63;
  const int bh = blockIdx.x, b = bh >> 4, h = bh & 15;
  const int q0 = blockIdx.y * 128 + wv * 16;
  const unsigned short* qb = qg  + (size_t)bh * SEQ * HD;
  const unsigned short* kb = kg  + (size_t)bh * SEQ * HD;
  const unsigned short* vb = vtg + (size_t)bh * HD * SEQ;
  const int* mp = amask + b * SEQ;
  unsigned short* myp = pls[wv];

  const int lcol = ln & 15, g = ln >> 4, lc8 = g * 8, lrow4 = g * 4;
  const int sw = (lcol & 7) << 3;              // read-side XOR (ushort units)
  const float* bprow = rpb + (size_t)h * SEQ * SEQ + (size_t)(q0 + lcol) * SEQ;

  const int srr = ln >> 3;                     // row within the 8-row chunk
  const int scc = (ln & 7) ^ srr;              // pre-swizzled global 8-ushort chunk

  bf16x8 aq0 = *reinterpret_cast<const bf16x8*>(qb + (size_t)(q0 + lcol) * HD + lc8);
  bf16x8 aq1 = *reinterpret_cast<const bf16x8*>(qb + (size_t)(q0 + lcol) * HD + 32 + lc8);

  f32x4 o[4] = {};
  float m = -1e30f, l = 0.f;

  auto stage = [&](int buf, int kt) {
    int row = wv * 8 + srr;
    glds16(kb + (size_t)(kt + row) * HD + scc * 8, &smK[buf][wv * 512]);
    glds16(vb + (size_t)row * SEQ + kt + scc * 8, &smV[buf][wv * 512]);
  };

  stage(0, 0);
  __syncthreads();

  for (int t = 0; t < SEQ / 64; t++) {
    const int cur = t & 1;
    const int kt = t * 64;
    float4 bv4[4]; int4 mv[4];
#pragma unroll
    for (int j = 0; j < 4; j++) {
      bv4[j] = *reinterpret_cast<const float4*>(bprow + kt + j * 16 + lrow4);
      mv[j]  = *reinterpret_cast<const int4*>(mp + kt + j * 16 + lrow4);
    }
    if (t < SEQ / 64 - 1) stage(cur ^ 1, kt + 64);

    f32x4 s[4];
#pragma unroll
    for (int j = 0; j < 4; j++) {
      int r = j * 16 + lcol;
      bf16x8 bk0 = *reinterpret_cast<const bf16x8*>(&smK[cur][r * 64 + (lc8 ^ sw)]);
      bf16x8 bk1 = *reinterpret_cast<const bf16x8*>(&smK[cur][r * 64 + ((32 + lc8) ^ sw)]);
      f32x4 z = {0.f, 0.f, 0.f, 0.f};
      z = __builtin_amdgcn_mfma_f32_16x16x32_bf16(bk0, aq0, z, 0, 0, 0);  // A=K, B=Q -> S^T
      z = __builtin_amdgcn_mfma_f32_16x16x32_bf16(bk1, aq1, z, 0, 0, 0);
      s[j] = z;
    }
#pragma unroll
    for (int j = 0; j < 4; j++) {
      s[j][0] = mv[j].x ? s[j][0] + bv4[j].x : -1e30f;
      s[j][1] = mv[j].y ? s[j][1] + bv4[j].y : -1e30f;
      s[j][2] = mv[j].z ? s[j][2] + bv4[j].z : -1e30f;
      s[j][3] = mv[j].w ? s[j][3] + bv4[j].w : -1e30f;
    }
    float pm = fmaxf(fmaxf(fmaxf(s[0][0], s[0][1]), fmaxf(s[0][2], s[0][3])),
                     fmaxf(fmaxf(s[1][0], s[1][1]), fmaxf(s[1][2], s[1][3])));
    pm = fmaxf(pm, fmaxf(fmaxf(fmaxf(s[2][0], s[2][1]), fmaxf(s[2][2], s[2][3])),
                         fmaxf(fmaxf(s[3][0], s[3][1]), fmaxf(s[3][2], s[3][3]))));
    pm = fmaxf(pm, __shfl_xor(pm, 16));
    pm = fmaxf(pm, __shfl_xor(pm, 32));
    // T13 defer-max (first-tile guard): rescale only on real max growth
    if (m < -1e29f || !__all(pm - m <= 8.0f)) {
      float mn = fmaxf(m, pm);
      float fr = __expf(m - mn);
      m = mn;
      l *= fr;
      float frq[4];
#pragma unroll
      for (int r = 0; r < 4; r++) frq[r] = __shfl(fr, lrow4 + r);
#pragma unroll
      for (int d = 0; d < 4; d++)
#pragma unroll
        for (int r = 0; r < 4; r++) o[d][r] *= frq[r];
    }
    float rs = 0.f;
#pragma unroll
    for (int j = 0; j < 4; j++)
#pragma unroll
      for (int r = 0; r < 4; r++) {
        float p = __expf(s[j][r] - m);
        s[j][r] = p;
        rs += p;
      }
    rs += __shfl_xor(rs, 16);
    rs += __shfl_xor(rs, 32);
    l += rs;
#pragma unroll
    for (int j = 0; j < 4; j++) {
      us4 po = { f2bf(s[j][0]), f2bf(s[j][1]), f2bf(s[j][2]), f2bf(s[j][3]) };
      *reinterpret_cast<us4*>(myp + lcol * PSTR + j * 16 + lrow4) = po;
    }
    asm volatile("s_waitcnt lgkmcnt(0)" ::: "memory");
    __builtin_amdgcn_sched_barrier(0);
#pragma unroll
    for (int c = 0; c < 2; c++) {
      bf16x8 ap = *reinterpret_cast<const bf16x8*>(myp + lcol * PSTR + c * 32 + lc8);
#pragma unroll
      for (int d = 0; d < 4; d++) {
        int vr = d * 16 + lcol;
        bf16x8 bvv = *reinterpret_cast<const bf16x8*>(&smV[cur][vr * 64 + ((c * 32 + lc8) ^ sw)]);
        o[d] = __builtin_amdgcn_mfma_f32_16x16x32_bf16(ap, bvv, o[d], 0, 0, 0);
      }
    }
    __syncthreads();   // drains prefetch vmcnt + P-LDS; swaps buffers
  }
  float linv = 1.0f / l;
  float lq[4];
#pragma unroll
  for (int r = 0; r < 4; r++) lq[r] = __shfl(linv, lrow4 + r);
#pragma unroll
  for (int d = 0; d < 4; d++)
#pragma unroll
    for (int r = 0; r < 4; r++)
      outh[(size_t)(b * SEQ + q0 + lrow4 + r) * DIM + h * HD + d * 16 + lcol] = f2bf(o[d][r] * lq[r]);
}

// ---------------- host ----------------
extern "C" void kernel_launch(void* const* d_in, const int* in_sizes, int n_in,
                              void* d_out, int out_size, void* d_ws, size_t ws_size,
                              hipStream_t stream)
{
  const float* x      = (const float*)d_in[0];
  const float* rpb    = (const float*)d_in[1];
  const int*   amask  = (const int*)d_in[2];
  const float* n1w    = (const float*)d_in[3];
  const float* n1b    = (const float*)d_in[4];
  const float* qkv_w  = (const float*)d_in[5];
  const float* q_bias = (const float*)d_in[6];
  const float* v_bias = (const float*)d_in[7];
  const float* proj_w = (const float*)d_in[8];
  const float* proj_b = (const float*)d_in[9];
  const float* n2w    = (const float*)d_in[10];
  const float* n2b    = (const float*)d_in[11];
  const float* w1     = (const float*)d_in[12];
  const float* b1     = (const float*)d_in[13];
  const float* w2     = (const float*)d_in[14];
  const float* b2     = (const float*)d_in[15];
  float* out = (float*)d_out;

  char* ws = (char*)d_ws;
  size_t off = 0;
  auto alloc = [&](size_t bytes) { char* p = ws + off; off += (bytes + 255) & ~(size_t)255; return p; };
  unsigned short* xn1    = (unsigned short*)alloc((size_t)ROWS * DIM * 2);
  unsigned short* xn2    = (unsigned short*)alloc((size_t)ROWS * DIM * 2);
  unsigned short* wqkv_h = (unsigned short*)alloc((size_t)3 * DIM * DIM * 2);
  unsigned short* wproj_h= (unsigned short*)alloc((size_t)DIM * DIM * 2);
  unsigned short* w1_h   = (unsigned short*)alloc((size_t)HIDDEN * DIM * 2);
  unsigned short* w2_h   = (unsigned short*)alloc((size_t)DIM * HIDDEN * 2);
  unsigned short* qh     = (unsigned short*)alloc((size_t)ROWS * DIM * 2);
  unsigned short* kh     = (unsigned short*)alloc((size_t)ROWS * DIM * 2);
  unsigned short* vth    = (unsigned short*)alloc((size_t)ROWS * DIM * 2);
  unsigned short* attn_h = (unsigned short*)alloc((size_t)ROWS * DIM * 2);
  float*          xres   = (float*)alloc((size_t)ROWS * DIM * 4);
  unsigned short* hmid   = (unsigned short*)alloc((size_t)ROWS * HIDDEN * 2);

  // all weight conversions in one launch
  cvt_all<<<2048, 256, 0, stream>>>(qkv_w, proj_w, w1, w2, wqkv_h, wproj_h, w1_h, w2_h);

  // LN1
  ln_kernel<<<ROWS, 256, 0, stream>>>(x, n1w, n1b, xn1);
  // QKV GEMM (M=4096, N=3072, K=1024) -- 768 blocks
  gemm128<0, 128><<<dim3(ROWS / 128, 3 * DIM / 128), 256, 0, stream>>>(
      xn1, wqkv_h, DIM, 3 * DIM, nullptr, nullptr, nullptr, nullptr, qh, kh, vth, q_bias, v_bias);
  // attention -- grid (bh, qblock): XCD = bh%8 -> per-head K/V/rpb locality
  attn_kernel<<<dim3(BATCH * NHEAD, SEQ / 128), 512, 0, stream>>>(qh, kh, vth, rpb, amask, attn_h);
  // proj GEMM + residual -> x_res (fp32) -- BN=64 -> 512 blocks
  gemm128<1, 64><<<dim3(ROWS / 128, DIM / 64), 256, 0, stream>>>(
      attn_h, wproj_h, DIM, DIM, proj_b, x, xres, nullptr, nullptr, nullptr, nullptr, nullptr, nullptr);
  // LN2
  ln_kernel<<<ROWS, 256, 0, stream>>>(xres, n2w, n2b, xn2);
  // MLP1 + GELU -- 1024 blocks
  gemm128<2, 128><<<dim3(ROWS / 128, HIDDEN / 128), 256, 0, stream>>>(
      xn2, w1_h, DIM, HIDDEN, b1, nullptr, nullptr, hmid, nullptr, nullptr, nullptr, nullptr, nullptr);
  // MLP2 + residual -> out -- BN=64 -> 512 blocks
  gemm128<3, 64><<<dim3(ROWS / 128, DIM / 64), 256, 0, stream>>>(
      hmid, w2_h, HIDDEN, DIM, b2, xres, out, nullptr, nullptr, nullptr, nullptr, nullptr, nullptr);
}